// Round 5
// baseline (2254.226 us; speedup 1.0000x reference)
//
#include <hip/hip_runtime.h>
#include <hip/hip_bf16.h>

typedef __attribute__((ext_vector_type(8))) short short8;
typedef __attribute__((ext_vector_type(4))) short short4_;
typedef __attribute__((ext_vector_type(4))) float float4_;

#define CH 64
#define HH 256
#define WW 256
#define HW (HH*WW)
#define CHW (CH*HW)

#define TW 16
#define TH 8
#define XPW 20
#define XPH 12
#define NXP 240        // x/qkv halo set (halo 2)
#define OPW 18
#define OPH 10
#define NOP 180        // out1 set (halo 1)
#define QS 36          // q/k/v chunk row stride (shorts), 32 ch used
#define OS 72          // out1 row stride (shorts), 16B-aligned rows
#define TS 17          // tbuf row stride (floats)

// LDS layout (short offsets)
#define KBUF_OFF 0      // 8640 shorts: k then v chunks; tbuf(float) overlays at conv
#define QBUF_OFF 8640   // 8640 shorts: q chunks
#define O1_OFF   8640   // 12960 shorts: out1 (overlays qbuf after dots done)
#define WBUF_OFF 21600  // 9216 shorts: conv B-frags for current nt
#define SMEM_SHORTS 30816   // 61632 B

__device__ __forceinline__ float b2f(unsigned short u) {
    return __uint_as_float(((unsigned)u) << 16);
}
__device__ __forceinline__ short f2bs(float f) {
    __hip_bfloat16 h = __float2bfloat16(f);
    short s; __builtin_memcpy(&s, &h, 2); return s;
}

__global__ __launch_bounds__(256, 2) void fused_mfma(
    const float* __restrict__ x, const float* __restrict__ wqkv,
    const float* __restrict__ bqkv, const float* __restrict__ wmlp,
    float* __restrict__ out)
{
    __shared__ __align__(16) short smem[SMEM_SHORTS];
    short* kbuf = smem + KBUF_OFF;
    short* qbuf = smem + QBUF_OFF;
    short* o1b  = smem + O1_OFF;
    short* wbuf = smem + WBUF_OFF;
    float* tbuf = (float*)smem;          // overlays kbuf region during conv

    const int t    = threadIdx.x;
    const int w    = t >> 6;
    const int lane = t & 63;
    const int n16  = lane & 15;
    const int quad = lane >> 4;

    const int b   = blockIdx.z;
    const int gy0 = blockIdx.y * TH;
    const int gx0 = blockIdx.x * TW;
    const float* xb = x + (size_t)b * CHW;

    const int nmt = (w < 3) ? 4 : 3;     // 15 M-tiles over 4 waves

    // OOB bitmask for C-writes: bit (i*4+r) -> pixel (w*4+i)*16 + quad*4 + r
    unsigned okbits = 0;
    for (int i = 0; i < 4; ++i)
        for (int r = 0; r < 4; ++r) {
            int p = (w*4 + i)*16 + quad*4 + r;
            if (p < NXP) {
                int py = p / XPW, px = p % XPW;
                int gy = gy0 - 2 + py, gx = gx0 - 2 + px;
                if (((unsigned)gy < HH) && ((unsigned)gx < WW))
                    okbits |= 1u << (i*4 + r);
            }
        }

    // ---- A-frags for qkv GEMM: x patch in registers, bf16
    short8 afr[4][2];
    for (int i = 0; i < nmt; ++i) {
        int p  = (w*4 + i)*16 + n16;
        int py = p / XPW, px = p % XPW;
        int gy = gy0 - 2 + py, gx = gx0 - 2 + px;
        bool ok = ((unsigned)gy < HH) && ((unsigned)gx < WW);
        const float* xp = xb + gy*WW + gx;
        if (ok) {
            #pragma unroll
            for (int ks = 0; ks < 2; ++ks) {
                short8 a;
                #pragma unroll
                for (int j = 0; j < 8; ++j)
                    a[j] = f2bs(xp[(size_t)(ks*32 + quad*8 + j)*HW]);
                afr[i][ks] = a;
            }
        } else {
            #pragma unroll
            for (int ks = 0; ks < 2; ++ks) {
                short8 a;
                #pragma unroll
                for (int j = 0; j < 8; ++j) a[j] = 0;
                afr[i][ks] = a;
            }
        }
    }

    // GEMM one 32-channel chunk of section sec (0=q,1=k,2=v) into dst
    auto gemm_chunk = [&](int sec, int ch, short* dst) {
        for (int local = 0; local < 2; ++local) {
            const int ob = sec*64 + ch*32 + local*16;     // output-channel base
            short8 bfr[2];
            #pragma unroll
            for (int ks = 0; ks < 2; ++ks) {
                const float4_* wp4 = (const float4_*)(wqkv + (size_t)(ob + n16)*CH + ks*32 + quad*8);
                float4_ w0 = wp4[0], w1 = wp4[1];
                short8 bb;
                #pragma unroll
                for (int j = 0; j < 4; ++j) { bb[j] = f2bs(w0[j]); bb[4+j] = f2bs(w1[j]); }
                bfr[ks] = bb;
            }
            const float bias = bqkv[ob + n16];
            for (int i = 0; i < nmt; ++i) {
                float4_ c = {0.f, 0.f, 0.f, 0.f};
                c = __builtin_amdgcn_mfma_f32_16x16x32_bf16(afr[i][0], bfr[0], c, 0, 0, 0);
                c = __builtin_amdgcn_mfma_f32_16x16x32_bf16(afr[i][1], bfr[1], c, 0, 0, 0);
                #pragma unroll
                for (int r = 0; r < 4; ++r) {
                    int p = (w*4 + i)*16 + quad*4 + r;
                    bool ok = (okbits >> (i*4 + r)) & 1u;
                    dst[p*QS + local*16 + n16] = ok ? f2bs(c[r] + bias) : (short)0;
                }
            }
        }
    };

    // per-thread attention pixel (t < NOP)
    const int op_py = t / OPW, op_px = t % OPW;
    const int ogy = gy0 - 1 + op_py, ogx = gx0 - 1 + op_px;
    const bool oin = (t < NOP) && ((unsigned)ogy < HH) && ((unsigned)ogx < WW);
    const int xpix = (op_py + 1)*XPW + (op_px + 1);

    float dots[9];
    #pragma unroll
    for (int n = 0; n < 9; ++n) dots[n] = 0.f;

    // ---- Q/K chunks + dot accumulation
    for (int ch = 0; ch < 2; ++ch) {
        gemm_chunk(0, ch, qbuf);
        gemm_chunk(1, ch, kbuf);
        __syncthreads();
        if (oin) {
            #pragma unroll
            for (int g = 0; g < 8; ++g) {
                short4_ q4 = *(const short4_*)&qbuf[xpix*QS + g*4];
                float qv[4];
                #pragma unroll
                for (int j = 0; j < 4; ++j) qv[j] = b2f((unsigned short)q4[j]);
                #pragma unroll
                for (int n = 0; n < 9; ++n) {
                    int np = xpix + (n/3 - 1)*XPW + (n%3 - 1);
                    short4_ k4 = *(const short4_*)&kbuf[np*QS + g*4];
                    #pragma unroll
                    for (int j = 0; j < 4; ++j) dots[n] += qv[j] * b2f((unsigned short)k4[j]);
                }
            }
        }
        __syncthreads();
    }

    // ---- softmax (registers)
    float attn[9];
    if (oin) {
        float mx = -1e30f;
        #pragma unroll
        for (int n = 0; n < 9; ++n) { dots[n] *= 0.125f; mx = fmaxf(mx, dots[n]); }
        float se = 0.f;
        #pragma unroll
        for (int n = 0; n < 9; ++n) { attn[n] = __expf(dots[n] - mx); se += attn[n]; }
        float inv = 1.f / se;
        #pragma unroll
        for (int n = 0; n < 9; ++n) attn[n] *= inv;
    }

    // ---- V chunks + aggregation into out1 (bf16 LDS)
    for (int ch = 0; ch < 2; ++ch) {
        gemm_chunk(2, ch, kbuf);
        __syncthreads();
        if (t < NOP) {
            unsigned pk[16];
            if (oin) {
                float o1[32];
                const float* xr = xb + (size_t)(ch*32)*HW + ogy*WW + ogx;
                #pragma unroll
                for (int j = 0; j < 32; ++j) o1[j] = xr[(size_t)j*HW];   // residual
                #pragma unroll
                for (int n = 0; n < 9; ++n) {
                    float a = attn[n];
                    int np = xpix + (n/3 - 1)*XPW + (n%3 - 1);
                    #pragma unroll
                    for (int g = 0; g < 8; ++g) {
                        short4_ v4 = *(const short4_*)&kbuf[np*QS + g*4];
                        #pragma unroll
                        for (int j = 0; j < 4; ++j) o1[g*4 + j] += a * b2f((unsigned short)v4[j]);
                    }
                }
                #pragma unroll
                for (int g2 = 0; g2 < 16; ++g2)
                    pk[g2] = (unsigned)(unsigned short)f2bs(o1[2*g2]) |
                             ((unsigned)(unsigned short)f2bs(o1[2*g2+1]) << 16);
            } else {
                #pragma unroll
                for (int g2 = 0; g2 < 16; ++g2) pk[g2] = 0u;  // image-OOB -> 0 (conv zero-pad)
            }
            unsigned* dst = (unsigned*)&o1b[t*OS + ch*32];
            #pragma unroll
            for (int g2 = 0; g2 < 16; ++g2) dst[g2] = pk[g2];
        }
        __syncthreads();
    }

    // ---- 3x3 conv 64->64 as implicit GEMM (K = 576 tap-major) + ReLU
    for (int nt = 0; nt < 4; ++nt) {
        // stage this nt's B-frags into wbuf: wbuf[ks*512 + l*8 + j]
        for (int e = t; e < 9216; e += 256) {
            int ks = e >> 9, rem = e & 511;
            int l = rem >> 3, j = rem & 7;
            int o   = nt*16 + (l & 15);
            int cin = (ks & 1)*32 + (l >> 4)*8 + j;
            int tap = ks >> 1;
            wbuf[e] = f2bs(wmlp[(size_t)o*576 + cin*9 + tap]);
        }
        __syncthreads();

        float4_ acc0 = {0.f,0.f,0.f,0.f}, acc1 = {0.f,0.f,0.f,0.f};
        const int mtc0 = w*2, mtc1 = w*2 + 1;
        for (int ks = 0; ks < 18; ++ks) {
            int tap = ks >> 1;
            int cin0 = (ks & 1)*32 + quad*8;
            int dy = tap/3 - 1, dx = tap%3 - 1;
            short8 bb = *(const short8*)&wbuf[ks*512 + lane*8];
            short8 a0 = *(const short8*)&o1b[((mtc0 + 1 + dy)*OPW + (n16 + 1 + dx))*OS + cin0];
            acc0 = __builtin_amdgcn_mfma_f32_16x16x32_bf16(a0, bb, acc0, 0, 0, 0);
            short8 a1 = *(const short8*)&o1b[((mtc1 + 1 + dy)*OPW + (n16 + 1 + dx))*OS + cin0];
            acc1 = __builtin_amdgcn_mfma_f32_16x16x32_bf16(a1, bb, acc1, 0, 0, 0);
        }
        // C-frags -> tbuf (fp32, ReLU). row = q*4+r is the pixel column tx.
        #pragma unroll
        for (int r = 0; r < 4; ++r) {
            tbuf[(mtc0*16 + quad*4 + r)*TS + n16] = fmaxf(acc0[r], 0.f);
            tbuf[(mtc1*16 + quad*4 + r)*TS + n16] = fmaxf(acc1[r], 0.f);
        }
        __syncthreads();
        // coalesced store: 128 px x 16 ch fp32
        {
            int pl = t & 127, oh = t >> 7;
            int ty_ = pl >> 4, tx_ = pl & 15;
            float* op = out + (size_t)b*CHW + (size_t)(nt*16)*HW
                        + (size_t)(gy0 + ty_)*WW + (gx0 + tx_);
            #pragma unroll
            for (int ii = 0; ii < 8; ++ii) {
                int o = oh*8 + ii;
                op[(size_t)o*HW] = tbuf[pl*TS + o];
            }
        }
        __syncthreads();
    }
}

extern "C" void kernel_launch(void* const* d_in, const int* in_sizes, int n_in,
                              void* d_out, int out_size, void* d_ws, size_t ws_size,
                              hipStream_t stream) {
    const float* x    = (const float*)d_in[0];
    const float* wqkv = (const float*)d_in[1];
    const float* bqkv = (const float*)d_in[2];
    const float* wmlp = (const float*)d_in[3];
    float* outp = (float*)d_out;

    dim3 grid(WW/TW, HH/TH, 4);
    fused_mfma<<<grid, 256, 0, stream>>>(x, wqkv, bqkv, wmlp, outp);
}

// Round 6
// 1684.387 us; speedup vs baseline: 1.3383x; 1.3383x over previous
//
#include <hip/hip_runtime.h>
#include <hip/hip_bf16.h>

typedef __attribute__((ext_vector_type(8))) short short8;
typedef __attribute__((ext_vector_type(4))) short short4_;
typedef __attribute__((ext_vector_type(4))) float float4_;

#define CH 64
#define HH 256
#define WW 256
#define HW (HH*WW)
#define CHW (CH*HW)

#define TW 16
#define TH 8
#define XPW 20
#define XPH 12
#define NXP 240        // x/qkv halo set (halo 2)
#define OPW 18
#define OPH 10
#define NOP 180        // out1 set (halo 1)

#define XLS 72         // x LDS row stride (shorts) -> 144 B, 16B aligned
#define KQS 18         // k/q chunk row stride (shorts): 16 ch + 2 pad
#define O1S 72         // out1 row stride (shorts)
#define TSF 33         // tbuf row stride (floats)

// ws layout (bytes): wsq bf16 [0,24576) ; wsm bf16 [24576, 98304)
#define WSQ_SHORTS 12288
#define WSM_SHORTS 36864

__device__ __forceinline__ float b2f(unsigned short u) {
    return __uint_as_float(((unsigned)u) << 16);
}
__device__ __forceinline__ short f2bs(float f) {
    __hip_bfloat16 h = __float2bfloat16(f);
    short s; __builtin_memcpy(&s, &h, 2); return s;
}

// ---- prep: pack wqkv/wmlp to bf16 in exact B-fragment order -----------------
__global__ void prep_pack(const float* __restrict__ wqkv,
                          const float* __restrict__ wmlp,
                          short* __restrict__ wsq, short* __restrict__ wsm) {
    int idx = blockIdx.x * blockDim.x + threadIdx.x;
    int stride = gridDim.x * blockDim.x;
    // wsq[((sec*4+q16)*2+ks)*512 + lane*8 + j] =
    //   wqkv[(sec*64+q16*16+(lane&15))*64 + ks*32 + (lane>>4)*8 + j]
    for (int e = idx; e < WSQ_SHORTS; e += stride) {
        int j = e & 7, lane = (e >> 3) & 63;
        int ks = (e >> 9) & 1, q16 = (e >> 10) & 3, sec = e >> 12;
        int row = sec*64 + q16*16 + (lane & 15);
        int kk  = ks*32 + (lane >> 4)*8 + j;
        wsq[e] = f2bs(wqkv[(size_t)row*64 + kk]);
    }
    // wsm[(nt*18+ks)*512 + lane*8 + j] = wmlp[o*576 + cin*9 + tap]
    for (int e = idx; e < WSM_SHORTS; e += stride) {
        int j = e & 7, lane = (e >> 3) & 63;
        int rest = e >> 9;            // 0..71
        int nt = rest / 18, ks = rest % 18;
        int o   = nt*16 + (lane & 15);
        int cin = (ks & 1)*32 + (lane >> 4)*8 + j;
        int tap = ks >> 1;
        wsm[e] = f2bs(wmlp[(size_t)o*576 + cin*9 + tap]);
    }
}

// ---- fused kernel -----------------------------------------------------------
__global__ __launch_bounds__(256, 3) void fused_mfma(
    const float* __restrict__ x, const short* __restrict__ wsq,
    const float* __restrict__ bqkv, const short* __restrict__ wsm,
    float* __restrict__ out)
{
    __shared__ __align__(16) short smem[21600];      // 43200 B
    short* xls  = smem;                              // [240][72] (phase X only)
    short* kbuf = smem;                              // [240][18]
    short* qbuf = smem + 4320;                       // [240][18]
    short* o1b  = smem + 8640;                       // [180][72]
    float* tbuf = (float*)smem;                      // [128][33] (conv epilogue)

    const int t    = threadIdx.x;
    const int w    = t >> 6;
    const int lane = t & 63;
    const int n16  = lane & 15;
    const int quad = lane >> 4;

    const int b   = blockIdx.z;
    const int gy0 = blockIdx.y * TH;
    const int gx0 = blockIdx.x * TW;
    const float* xb = x + (size_t)b * CHW;

    const int nmt = (w < 3) ? 4 : 3;     // 15 M-tiles over 4 waves

    // ---- phase X: stage x halo tile into LDS bf16, coalesced float4 loads
    for (int slot = t; slot < 64*12*6; slot += 256) {
        int s6 = slot % 6, y = (slot / 6) % 12, c = slot / 72;
        int gy = gy0 - 2 + y;
        int gxb = gx0 - 4 + s6*4;
        float v[4];
        bool gyok = (unsigned)gy < HH;
        if (gyok && gxb >= 0 && gxb + 3 < WW) {
            float4_ f4 = *(const float4_*)(xb + (size_t)c*HW + gy*WW + gxb);
            v[0]=f4[0]; v[1]=f4[1]; v[2]=f4[2]; v[3]=f4[3];
        } else {
            #pragma unroll
            for (int i = 0; i < 4; ++i) {
                int gx = gxb + i;
                v[i] = (gyok && (unsigned)gx < WW) ? xb[(size_t)c*HW + gy*WW + gx] : 0.f;
            }
        }
        #pragma unroll
        for (int i = 0; i < 4; ++i) {
            int pxc = s6*4 + i - 2;
            if ((unsigned)pxc < XPW)
                xls[(y*XPW + pxc)*XLS + c] = f2bs(v[i]);
        }
    }
    __syncthreads();

    // OOB bitmask: bit(i*4+r) -> halo pixel (w*4+i)*16 + quad*4 + r
    unsigned okbits = 0;
    for (int i = 0; i < 4; ++i)
        for (int r = 0; r < 4; ++r) {
            int p = (w*4 + i)*16 + quad*4 + r;
            if (p < NXP) {
                int gy = gy0 - 2 + p / XPW, gx = gx0 - 2 + p % XPW;
                if (((unsigned)gy < HH) && ((unsigned)gx < WW))
                    okbits |= 1u << (i*4 + r);
            }
        }

    // ---- A-frags (from LDS) + residual capture (bf16 regs)
    short8 afr[4][2];
    for (int i = 0; i < nmt; ++i) {
        int p = (w*4 + i)*16 + n16;
        #pragma unroll
        for (int ks = 0; ks < 2; ++ks)
            afr[i][ks] = *(const short8*)&xls[p*XLS + ks*32 + quad*8];
    }
    // per-thread attention pixel
    const int op_py = t / OPW, op_px = t % OPW;
    const int ogy = gy0 - 1 + op_py, ogx = gx0 - 1 + op_px;
    const bool oin = (t < NOP) && ((unsigned)ogy < HH) && ((unsigned)ogx < WW);
    const int xpix = (op_py + 1)*XPW + (op_px + 1);
    short8 resi[8];
    if (t < NOP) {
        #pragma unroll
        for (int g = 0; g < 8; ++g)
            resi[g] = *(const short8*)&xls[xpix*XLS + g*8];
    }
    __syncthreads();   // xls dead; k/q/o1b regions may now be written

    // gemm one 16-outch chunk of section sec (0=q,1=k,2=v) into dst
    auto gemm16 = [&](int sec, int q16, short* dst) {
        short8 b0 = *(const short8*)&wsq[(((sec*4 + q16)*2 + 0) << 9) + lane*8];
        short8 b1 = *(const short8*)&wsq[(((sec*4 + q16)*2 + 1) << 9) + lane*8];
        float bias = bqkv[sec*64 + q16*16 + n16];
        for (int i = 0; i < nmt; ++i) {
            float4_ c = {0.f, 0.f, 0.f, 0.f};
            c = __builtin_amdgcn_mfma_f32_16x16x32_bf16(afr[i][0], b0, c, 0, 0, 0);
            c = __builtin_amdgcn_mfma_f32_16x16x32_bf16(afr[i][1], b1, c, 0, 0, 0);
            #pragma unroll
            for (int r = 0; r < 4; ++r) {
                int p = (w*4 + i)*16 + quad*4 + r;
                bool ok = (okbits >> (i*4 + r)) & 1u;
                dst[p*KQS + n16] = ok ? f2bs(c[r] + bias) : (short)0;
            }
        }
    };

    // ---- QK rounds (4 x 16 channels) + dot accumulation
    float dots[9];
    #pragma unroll
    for (int n = 0; n < 9; ++n) dots[n] = 0.f;

    for (int q16 = 0; q16 < 4; ++q16) {
        gemm16(0, q16, qbuf);
        gemm16(1, q16, kbuf);
        __syncthreads();
        if (oin) {
            #pragma unroll
            for (int g = 0; g < 4; ++g) {
                short4_ q4 = *(const short4_*)&qbuf[xpix*KQS + g*4];
                float qv[4];
                #pragma unroll
                for (int j = 0; j < 4; ++j) qv[j] = b2f((unsigned short)q4[j]);
                #pragma unroll
                for (int n = 0; n < 9; ++n) {
                    int np = xpix + (n/3 - 1)*XPW + (n%3 - 1);
                    short4_ k4 = *(const short4_*)&kbuf[np*KQS + g*4];
                    #pragma unroll
                    for (int j = 0; j < 4; ++j) dots[n] += qv[j] * b2f((unsigned short)k4[j]);
                }
            }
        }
        __syncthreads();
    }

    // ---- softmax (registers)
    float attn[9];
    if (oin) {
        float mx = -1e30f;
        #pragma unroll
        for (int n = 0; n < 9; ++n) { dots[n] *= 0.125f; mx = fmaxf(mx, dots[n]); }
        float se = 0.f;
        #pragma unroll
        for (int n = 0; n < 9; ++n) { attn[n] = __expf(dots[n] - mx); se += attn[n]; }
        float inv = 1.f / se;
        #pragma unroll
        for (int n = 0; n < 9; ++n) attn[n] *= inv;
    }

    // ---- V rounds (4 x 16 channels): gemm v -> aggregate into o1b (bf16)
    for (int q16 = 0; q16 < 4; ++q16) {
        gemm16(2, q16, kbuf);
        __syncthreads();
        if (t < NOP) {
            unsigned pk[8];
            if (oin) {
                float o1[16];
                #pragma unroll
                for (int h = 0; h < 2; ++h) {
                    short8 rg = resi[q16*2 + h];
                    #pragma unroll
                    for (int j = 0; j < 8; ++j) o1[h*8 + j] = b2f((unsigned short)rg[j]);
                }
                #pragma unroll
                for (int n = 0; n < 9; ++n) {
                    float a = attn[n];
                    int np = xpix + (n/3 - 1)*XPW + (n%3 - 1);
                    #pragma unroll
                    for (int g = 0; g < 4; ++g) {
                        short4_ v4 = *(const short4_*)&kbuf[np*KQS + g*4];
                        #pragma unroll
                        for (int j = 0; j < 4; ++j) o1[g*4 + j] += a * b2f((unsigned short)v4[j]);
                    }
                }
                #pragma unroll
                for (int g2 = 0; g2 < 8; ++g2)
                    pk[g2] = (unsigned)(unsigned short)f2bs(o1[2*g2]) |
                             ((unsigned)(unsigned short)f2bs(o1[2*g2+1]) << 16);
            } else {
                #pragma unroll
                for (int g2 = 0; g2 < 8; ++g2) pk[g2] = 0u;   // image-OOB -> conv zero-pad
            }
            unsigned* dst = (unsigned*)&o1b[t*O1S + q16*16];
            #pragma unroll
            for (int g2 = 0; g2 < 8; ++g2) dst[g2] = pk[g2];
        }
        __syncthreads();
    }

    // ---- 3x3 conv 64->64 as one MFMA burst (K=576 tap-major), B from global
    float4_ acc[4][2];
    #pragma unroll
    for (int nt = 0; nt < 4; ++nt) {
        acc[nt][0] = (float4_){0.f,0.f,0.f,0.f};
        acc[nt][1] = (float4_){0.f,0.f,0.f,0.f};
    }
    const int mtc0 = w*2, mtc1 = w*2 + 1;
    for (int ks = 0; ks < 18; ++ks) {
        int tap = ks >> 1;
        int dy = tap/3 - 1, dx = tap%3 - 1;
        int cin0 = (ks & 1)*32 + quad*8;
        int pixA = (mtc0 + 1 + dy)*OPW + (n16 + 1 + dx);
        int pixB = (mtc1 + 1 + dy)*OPW + (n16 + 1 + dx);
        short8 a0 = *(const short8*)&o1b[pixA*O1S + cin0];
        short8 a1 = *(const short8*)&o1b[pixB*O1S + cin0];
        #pragma unroll
        for (int nt = 0; nt < 4; ++nt) {
            short8 bb = *(const short8*)&wsm[((nt*18 + ks) << 9) + lane*8];
            acc[nt][0] = __builtin_amdgcn_mfma_f32_16x16x32_bf16(a0, bb, acc[nt][0], 0, 0, 0);
            acc[nt][1] = __builtin_amdgcn_mfma_f32_16x16x32_bf16(a1, bb, acc[nt][1], 0, 0, 0);
        }
    }

    // ---- epilogue: two 32-channel halves through tbuf, coalesced stores
    #pragma unroll
    for (int half = 0; half < 2; ++half) {
        #pragma unroll
        for (int ntl = 0; ntl < 2; ++ntl) {
            int nt = half*2 + ntl;
            #pragma unroll
            for (int r = 0; r < 4; ++r) {
                tbuf[(mtc0*16 + quad*4 + r)*TSF + ntl*16 + n16] = fmaxf(acc[nt][0][r], 0.f);
                tbuf[(mtc1*16 + quad*4 + r)*TSF + ntl*16 + n16] = fmaxf(acc[nt][1][r], 0.f);
            }
        }
        __syncthreads();
        {
            int pl = t & 127, oh = t >> 7;
            int ty_ = pl >> 4, tx_ = pl & 15;
            float* op = out + (size_t)b*CHW + (size_t)(half*32 + oh*16)*HW
                        + (size_t)(gy0 + ty_)*WW + (gx0 + tx_);
            #pragma unroll
            for (int ii = 0; ii < 16; ++ii)
                op[(size_t)ii*HW] = tbuf[pl*TSF + oh*16 + ii];
        }
        __syncthreads();
    }
}

extern "C" void kernel_launch(void* const* d_in, const int* in_sizes, int n_in,
                              void* d_out, int out_size, void* d_ws, size_t ws_size,
                              hipStream_t stream) {
    const float* x    = (const float*)d_in[0];
    const float* wqkv = (const float*)d_in[1];
    const float* bqkv = (const float*)d_in[2];
    const float* wmlp = (const float*)d_in[3];
    float* outp = (float*)d_out;

    short* wsq = (short*)d_ws;                      // 24576 B
    short* wsm = wsq + WSQ_SHORTS;                  // 73728 B  (total 98304 B)

    prep_pack<<<64, 256, 0, stream>>>(wqkv, wmlp, wsq, wsm);

    dim3 grid(WW/TW, HH/TH, 4);
    fused_mfma<<<grid, 256, 0, stream>>>(x, wsq, bqkv, wsm, outp);
}

// Round 7
// 370.595 us; speedup vs baseline: 6.0827x; 4.5451x over previous
//
#include <hip/hip_runtime.h>
#include <hip/hip_bf16.h>

typedef __attribute__((ext_vector_type(8))) short short8;
typedef __attribute__((ext_vector_type(4))) short short4_;
typedef __attribute__((ext_vector_type(4))) float float4_;

#define CH 64
#define HH 256
#define WW 256
#define HW (HH*WW)
#define CHW (CH*HW)

#define TW 16
#define TH 8
#define XPW 20
#define XPH 12
#define NXP 240        // x/qkv halo set (halo 2)
#define OPW 18
#define OPH 10
#define NOP 180        // out1 set (halo 1)

#define XLS 72         // x LDS row stride (shorts) -> 144 B, 16B aligned
#define KQS 18         // k/q chunk row stride (shorts): 16 ch + 2 pad
#define O1S 72         // out1 row stride (shorts)
#define TSF 33         // tbuf row stride (floats)

// ws layout: wsq bf16 [0,24576) ; wsm bf16 [24576, 98304)
#define WSQ_SHORTS 12288
#define WSM_SHORTS 36864

__device__ __forceinline__ float b2f(unsigned short u) {
    return __uint_as_float(((unsigned)u) << 16);
}
__device__ __forceinline__ short f2bs(float f) {
    __hip_bfloat16 h = __float2bfloat16(f);
    short s; __builtin_memcpy(&s, &h, 2); return s;
}

// ---- prep: pack wqkv/wmlp to bf16 in exact B-fragment order -----------------
__global__ void prep_pack(const float* __restrict__ wqkv,
                          const float* __restrict__ wmlp,
                          short* __restrict__ wsq, short* __restrict__ wsm) {
    int idx = blockIdx.x * blockDim.x + threadIdx.x;
    int stride = gridDim.x * blockDim.x;
    for (int e = idx; e < WSQ_SHORTS; e += stride) {
        int j = e & 7, lane = (e >> 3) & 63;
        int ks = (e >> 9) & 1, q16 = (e >> 10) & 3, sec = e >> 12;
        int row = sec*64 + q16*16 + (lane & 15);
        int kk  = ks*32 + (lane >> 4)*8 + j;
        wsq[e] = f2bs(wqkv[(size_t)row*64 + kk]);
    }
    for (int e = idx; e < WSM_SHORTS; e += stride) {
        int j = e & 7, lane = (e >> 3) & 63;
        int rest = e >> 9;            // 0..71
        int nt = rest / 18, ks = rest % 18;
        int o   = nt*16 + (lane & 15);
        int cin = (ks & 1)*32 + (lane >> 4)*8 + j;
        int tap = ks >> 1;
        wsm[e] = f2bs(wmlp[(size_t)o*576 + cin*9 + tap]);
    }
}

// ---- fused kernel -----------------------------------------------------------
__global__ __launch_bounds__(256, 3) void fused_mfma(
    const float* __restrict__ x, const short* __restrict__ wsq,
    const float* __restrict__ bqkv, const short* __restrict__ wsm,
    float* __restrict__ out)
{
    __shared__ __align__(16) short smem[21600];      // 43200 B
    short* xls  = smem;                              // [240][72] (phase X only)
    short* kbuf = smem;                              // [240][18]
    short* qbuf = smem + 4320;                       // [240][18]
    short* o1b  = smem + 8640;                       // [180][72]
    float* tbuf = (float*)smem;                      // [128][33] (conv epilogue)

    const int t    = threadIdx.x;
    const int w    = t >> 6;
    const int lane = t & 63;
    const int n16  = lane & 15;
    const int quad = lane >> 4;

    const int b   = blockIdx.z;
    const int gy0 = blockIdx.y * TH;
    const int gx0 = blockIdx.x * TW;
    const float* xb = x + (size_t)b * CHW;

    // NOTE: all 4 waves process exactly 4 M-tiles (16th tile is a clamped
    // dummy) so that every register-array index is compile-time static.
    // Dynamic-bound loops over register arrays (round 5/6) caused scratch
    // spills: WRITE_SIZE 188MB vs 67MB ideal.

    // ---- phase X: stage x halo tile into LDS bf16, coalesced float4 loads
    for (int slot = t; slot < 64*12*6; slot += 256) {
        int s6 = slot % 6, y = (slot / 6) % 12, c = slot / 72;
        int gy = gy0 - 2 + y;
        int gxb = gx0 - 4 + s6*4;
        float v[4];
        bool gyok = (unsigned)gy < HH;
        if (gyok && gxb >= 0 && gxb + 3 < WW) {
            float4_ f4 = *(const float4_*)(xb + (size_t)c*HW + gy*WW + gxb);
            v[0]=f4[0]; v[1]=f4[1]; v[2]=f4[2]; v[3]=f4[3];
        } else {
            #pragma unroll
            for (int i = 0; i < 4; ++i) {
                int gx = gxb + i;
                v[i] = (gyok && (unsigned)gx < WW) ? xb[(size_t)c*HW + gy*WW + gx] : 0.f;
            }
        }
        #pragma unroll
        for (int i = 0; i < 4; ++i) {
            int pxc = s6*4 + i - 2;
            if ((unsigned)pxc < XPW)
                xls[(y*XPW + pxc)*XLS + c] = f2bs(v[i]);
        }
    }
    __syncthreads();

    // OOB bitmask: bit(i*4+r) -> halo pixel (w*4+i)*16 + quad*4 + r
    unsigned okbits = 0;
    #pragma unroll
    for (int i = 0; i < 4; ++i)
        #pragma unroll
        for (int r = 0; r < 4; ++r) {
            int p = (w*4 + i)*16 + quad*4 + r;
            if (p < NXP) {
                int gy = gy0 - 2 + p / XPW, gx = gx0 - 2 + p % XPW;
                if (((unsigned)gy < HH) && ((unsigned)gx < WW))
                    okbits |= 1u << (i*4 + r);
            }
        }

    // ---- A-frags (from LDS, static-indexed) + residual capture
    short8 afr[4][2];
    #pragma unroll
    for (int i = 0; i < 4; ++i) {
        int p = (w*4 + i)*16 + n16;
        int pr = (p < NXP) ? p : 0;        // clamped dummy for wave3/i3
        #pragma unroll
        for (int ks = 0; ks < 2; ++ks)
            afr[i][ks] = *(const short8*)&xls[pr*XLS + ks*32 + quad*8];
    }
    // per-thread attention pixel
    const int op_py = t / OPW, op_px = t % OPW;
    const int ogy = gy0 - 1 + op_py, ogx = gx0 - 1 + op_px;
    const bool oin = (t < NOP) && ((unsigned)ogy < HH) && ((unsigned)ogx < WW);
    const int xpix = (op_py + 1)*XPW + (op_px + 1);
    short8 resi[8];
    if (t < NOP) {
        #pragma unroll
        for (int g = 0; g < 8; ++g)
            resi[g] = *(const short8*)&xls[xpix*XLS + g*8];
    }
    __syncthreads();   // xls dead; k/q/o1b regions may now be written

    // gemm one 16-outch chunk of section sec (0=q,1=k,2=v) into dst
    auto gemm16 = [&](int sec, int q16, short* dst) {
        short8 b0 = *(const short8*)&wsq[(((sec*4 + q16)*2 + 0) << 9) + lane*8];
        short8 b1 = *(const short8*)&wsq[(((sec*4 + q16)*2 + 1) << 9) + lane*8];
        float bias = bqkv[sec*64 + q16*16 + n16];
        #pragma unroll
        for (int i = 0; i < 4; ++i) {
            float4_ c = {0.f, 0.f, 0.f, 0.f};
            c = __builtin_amdgcn_mfma_f32_16x16x32_bf16(afr[i][0], b0, c, 0, 0, 0);
            c = __builtin_amdgcn_mfma_f32_16x16x32_bf16(afr[i][1], b1, c, 0, 0, 0);
            #pragma unroll
            for (int r = 0; r < 4; ++r) {
                int p = (w*4 + i)*16 + quad*4 + r;
                bool ok = (okbits >> (i*4 + r)) & 1u;
                if (p < NXP)                        // guard dummy tile
                    dst[p*KQS + n16] = ok ? f2bs(c[r] + bias) : (short)0;
            }
        }
    };

    // ---- QK rounds (4 x 16 channels) + dot accumulation
    float dots[9];
    #pragma unroll
    for (int n = 0; n < 9; ++n) dots[n] = 0.f;

    #pragma unroll
    for (int q16 = 0; q16 < 4; ++q16) {
        gemm16(0, q16, qbuf);
        gemm16(1, q16, kbuf);
        __syncthreads();
        if (oin) {
            #pragma unroll
            for (int g = 0; g < 4; ++g) {
                short4_ q4 = *(const short4_*)&qbuf[xpix*KQS + g*4];
                float qv[4];
                #pragma unroll
                for (int j = 0; j < 4; ++j) qv[j] = b2f((unsigned short)q4[j]);
                #pragma unroll
                for (int n = 0; n < 9; ++n) {
                    int np = xpix + (n/3 - 1)*XPW + (n%3 - 1);
                    short4_ k4 = *(const short4_*)&kbuf[np*KQS + g*4];
                    #pragma unroll
                    for (int j = 0; j < 4; ++j) dots[n] += qv[j] * b2f((unsigned short)k4[j]);
                }
            }
        }
        __syncthreads();
    }

    // ---- softmax (registers)
    float attn[9];
    if (oin) {
        float mx = -1e30f;
        #pragma unroll
        for (int n = 0; n < 9; ++n) { dots[n] *= 0.125f; mx = fmaxf(mx, dots[n]); }
        float se = 0.f;
        #pragma unroll
        for (int n = 0; n < 9; ++n) { attn[n] = __expf(dots[n] - mx); se += attn[n]; }
        float inv = 1.f / se;
        #pragma unroll
        for (int n = 0; n < 9; ++n) attn[n] *= inv;
    }

    // ---- V rounds (4 x 16 channels): gemm v -> aggregate into o1b (bf16)
    #pragma unroll
    for (int q16 = 0; q16 < 4; ++q16) {
        gemm16(2, q16, kbuf);
        __syncthreads();
        if (t < NOP) {
            unsigned pk[8];
            if (oin) {
                float o1[16];
                #pragma unroll
                for (int h = 0; h < 2; ++h) {
                    short8 rg = resi[q16*2 + h];
                    #pragma unroll
                    for (int j = 0; j < 8; ++j) o1[h*8 + j] = b2f((unsigned short)rg[j]);
                }
                #pragma unroll
                for (int n = 0; n < 9; ++n) {
                    float a = attn[n];
                    int np = xpix + (n/3 - 1)*XPW + (n%3 - 1);
                    #pragma unroll
                    for (int g = 0; g < 4; ++g) {
                        short4_ v4 = *(const short4_*)&kbuf[np*KQS + g*4];
                        #pragma unroll
                        for (int j = 0; j < 4; ++j) o1[g*4 + j] += a * b2f((unsigned short)v4[j]);
                    }
                }
                #pragma unroll
                for (int g2 = 0; g2 < 8; ++g2)
                    pk[g2] = (unsigned)(unsigned short)f2bs(o1[2*g2]) |
                             ((unsigned)(unsigned short)f2bs(o1[2*g2+1]) << 16);
            } else {
                #pragma unroll
                for (int g2 = 0; g2 < 8; ++g2) pk[g2] = 0u;   // image-OOB -> conv zero-pad
            }
            unsigned* dst = (unsigned*)&o1b[t*O1S + q16*16];
            #pragma unroll
            for (int g2 = 0; g2 < 8; ++g2) dst[g2] = pk[g2];
        }
        __syncthreads();
    }

    // ---- 3x3 conv 64->64 as one MFMA burst (K=576 tap-major), B from ws
    float4_ acc[4][2];
    #pragma unroll
    for (int nt = 0; nt < 4; ++nt) {
        acc[nt][0] = (float4_){0.f,0.f,0.f,0.f};
        acc[nt][1] = (float4_){0.f,0.f,0.f,0.f};
    }
    const int mtc0 = w*2, mtc1 = w*2 + 1;
    for (int ks = 0; ks < 18; ++ks) {
        int tap = ks >> 1;
        int dy = tap/3 - 1, dx = tap%3 - 1;
        int cin0 = (ks & 1)*32 + quad*8;
        int pixA = (mtc0 + 1 + dy)*OPW + (n16 + 1 + dx);
        int pixB = (mtc1 + 1 + dy)*OPW + (n16 + 1 + dx);
        short8 a0 = *(const short8*)&o1b[pixA*O1S + cin0];
        short8 a1 = *(const short8*)&o1b[pixB*O1S + cin0];
        #pragma unroll
        for (int nt = 0; nt < 4; ++nt) {
            short8 bb = *(const short8*)&wsm[((nt*18 + ks) << 9) + lane*8];
            acc[nt][0] = __builtin_amdgcn_mfma_f32_16x16x32_bf16(a0, bb, acc[nt][0], 0, 0, 0);
            acc[nt][1] = __builtin_amdgcn_mfma_f32_16x16x32_bf16(a1, bb, acc[nt][1], 0, 0, 0);
        }
    }

    // ---- epilogue: two 32-channel halves through tbuf, coalesced stores
    #pragma unroll
    for (int half = 0; half < 2; ++half) {
        #pragma unroll
        for (int ntl = 0; ntl < 2; ++ntl) {
            int nt = half*2 + ntl;
            #pragma unroll
            for (int r = 0; r < 4; ++r) {
                tbuf[(mtc0*16 + quad*4 + r)*TSF + ntl*16 + n16] = fmaxf(acc[nt][0][r], 0.f);
                tbuf[(mtc1*16 + quad*4 + r)*TSF + ntl*16 + n16] = fmaxf(acc[nt][1][r], 0.f);
            }
        }
        __syncthreads();
        {
            int pl = t & 127, oh = t >> 7;
            int ty_ = pl >> 4, tx_ = pl & 15;
            float* op = out + (size_t)b*CHW + (size_t)(half*32 + oh*16)*HW
                        + (size_t)(gy0 + ty_)*WW + (gx0 + tx_);
            #pragma unroll
            for (int ii = 0; ii < 16; ++ii)
                op[(size_t)ii*HW] = tbuf[pl*TSF + oh*16 + ii];
        }
        __syncthreads();
    }
}

extern "C" void kernel_launch(void* const* d_in, const int* in_sizes, int n_in,
                              void* d_out, int out_size, void* d_ws, size_t ws_size,
                              hipStream_t stream) {
    const float* x    = (const float*)d_in[0];
    const float* wqkv = (const float*)d_in[1];
    const float* bqkv = (const float*)d_in[2];
    const float* wmlp = (const float*)d_in[3];
    float* outp = (float*)d_out;

    short* wsq = (short*)d_ws;                      // 24576 B
    short* wsm = wsq + WSQ_SHORTS;                  // 73728 B  (total 98304 B)

    prep_pack<<<64, 256, 0, stream>>>(wqkv, wmlp, wsq, wsm);

    dim3 grid(WW/TW, HH/TH, 4);
    fused_mfma<<<grid, 256, 0, stream>>>(x, wsq, bqkv, wsm, outp);
}